// Round 15
// baseline (315.479 us; speedup 1.0000x reference)
//
#include <hip/hip_runtime.h>

// LSTM B=4096, T=512, I=2, H=50, O=3 — MFMA, round 15.
// Base = r13 (best, 273us): h plain bf16 (no lo-plane), per-t global x via
// writer wave (proven off-critical-path: its vmcnt drain hides under the
// compute waves' body), RS=144 (verified bank-uniform for b128 windows),
// exp2-direct epilogue, ONE barrier/t.
// r15 micro-cuts (issue work + chain depth inside the lockstep):
//  * 4 independent MFMA accumulators (1-deep chains) + pairwise adds.
//  * merged triple-product rcp: one rcp((1+ef)(1+ei)(eg+1)) serves both
//    sigma(f) and sigma(i)*tanh(g) -> 7 trans/cell (was 8).
//  * SoA epilogue: all 8 exp2 of both cells issued first, then tails.
// K map: k<50 h(bf16), 50/51 x-hi, 52/53 x-lo, 54 bias (B=1.0), else 0.
//   A (M) = scaled weight rows (hi/lo VGPR frags), m=col; B (N) = h, col=batch.
//   C: col=lane&15=batch, grp=lane>>4=unit-in-tile, reg=GATE.

typedef short bf16x8 __attribute__((ext_vector_type(8)));
typedef float f32x4  __attribute__((ext_vector_type(4)));

#define T_STEPS 512
#define HID     50
#define ROWS    16
#define RS      144                        // bytes per m-row (9 granules)
#define HBUF_SZ (ROWS * RS)                // 2304 B
#define HF_OFF  (2 * HBUF_SZ)              // 4608 B
#define ARENA_SZ (HF_OFF + ROWS * 64 * 4)  // 8704 B
#define NTHREADS 512

#define L2E  1.442695040888963f
#define L2E2 2.885390081777927f

// init-time RTN bf16 hi/lo split (lo short = hi(f), hi short = residual)
__device__ __forceinline__ unsigned pack_hilo(float f) {
    unsigned u  = __float_as_uint(f);
    unsigned hi = (u + 0x7fffu + ((u >> 16) & 1u)) >> 16;
    float    fh = __uint_as_float(hi << 16);
    float    rl = f - fh;
    unsigned ul = __float_as_uint(rl);
    unsigned lo = (ul + 0x7fffu + ((ul >> 16) & 1u)) >> 16;
    return (hi & 0xFFFFu) | (lo << 16);
}
// 1-instr packed bf16 RNE: low short = bf16(a), high short = bf16(b)
__device__ __forceinline__ unsigned cvt_pk_bf16(float a, float b) {
    unsigned r;
    asm("v_cvt_pk_bf16_f32 %0, %1, %2" : "=v"(r) : "v"(a), "v"(b));
    return r;
}

__global__ __launch_bounds__(NTHREADS) void lstm_mfma11_kernel(
    const float* __restrict__ x,     // [B,T,2]
    const float* __restrict__ W_ih,  // [200,2]
    const float* __restrict__ W_hh,  // [200,50]
    const float* __restrict__ b_ih,  // [200]
    const float* __restrict__ b_hh,  // [200]
    const float* __restrict__ W_fc,  // [3,50]
    const float* __restrict__ b_fc,  // [3]
    float* __restrict__ out)         // [B,3]
{
    __shared__ __align__(16) char arena[ARENA_SZ];

    const int tid  = threadIdx.x;
    const int lane = tid & 63;
    const int wvf  = tid >> 6;         // wave 0..7
    const int col  = lane & 15;        // C col = batch row; A row index m
    const int grp  = lane >> 4;        // k-group; C row-group = unit-in-tile
    const int b0   = blockIdx.x * ROWS;

    // ---- zero arena ----
    for (int i = tid; i < ARENA_SZ / 4; i += NTHREADS) ((int*)arena)[i] = 0;

    // ---- A-frags (scaled weights, hi/lo) for tiles tau = 2*wvf + tt ----
    bf16x8 awhi[2][2], awlo[2][2];   // [tt][kt]
    bool act[2];
#pragma unroll
    for (int tt = 0; tt < 2; ++tt) {
        const int tau = wvf * 2 + tt;
        act[tt] = (wvf < 7) && (tau * 4 < HID);
        const int u = tau * 4 + (col >> 2);
        const int g = col & 3;
        const float s = (g == 2) ? L2E2 : -L2E;   // fold gate scale into W
#pragma unroll
        for (int kt = 0; kt < 2; ++kt) {
            bf16x8 H, L;
#pragma unroll
            for (int e = 0; e < 8; ++e) {
                int k = kt * 32 + grp * 8 + e;
                float v = 0.f;
                if (act[tt] && u < HID) {
                    int j = g * HID + u;
                    if      (k < HID)  v = W_hh[j * HID + k];
                    else if (k == 50 || k == 52)  v = W_ih[2 * j + 0];
                    else if (k == 51 || k == 53)  v = W_ih[2 * j + 1];
                    else if (k == 54)  v = b_ih[j] + b_hh[j];
                }
                unsigned p = pack_hilo(v * s);
                H[e] = (short)(p & 0xFFFFu);
                L[e] = (short)(p >> 16);
            }
            awhi[tt][kt] = H;
            awlo[tt][kt] = L;
        }
    }

    __syncthreads();   // zeroing complete

    // const-1.0 at k=54 (byte 108), both buffers (bias multiplier)
    if (tid < 2 * ROWS) {
        int buf = tid >> 4, m = tid & 15;
        *(short*)(arena + buf * HBUF_SZ + m * RS + 108) = (short)0x3F80;
    }
    // x writer: wave 7, lanes 0..15 (lane = batch row)
    const bool xwriter = (wvf == 7) && (lane < 16);
    const float* xptr = x + (size_t)(b0 + lane) * (T_STEPS * 2);
    if (xwriter) {   // x(t=0) into buffer 0: hi at bytes 100..103, lo 104..107
        float2 xv = *(const float2*)xptr;
        unsigned xh = cvt_pk_bf16(xv.x, xv.y);
        float f0 = __uint_as_float(xh << 16);
        float f1 = __uint_as_float(xh & 0xFFFF0000u);
        unsigned xl = cvt_pk_bf16(xv.x - f0, xv.y - f1);
        *(unsigned*)(arena + lane * RS + 100) = xh;
        *(unsigned*)(arena + lane * RS + 104) = xl;
    }
    float2 xpre = xwriter ? *(const float2*)(xptr + 2) : make_float2(0.f, 0.f);

    float c2[2]   = {0.f, 0.f};
    float hreg[2] = {0.f, 0.f};

    __syncthreads();

    int pb = 0;
    for (int t = 0; t < T_STEPS; ++t) {
        char* db = arena + (pb ^ 1) * HBUF_SZ;

        if (wvf < 7) {
            // ---- B-frags: 2 ds_read_b128 (bf16 h plane), shared by tiles ----
            const char* hb = arena + pb * HBUF_SZ + col * RS + grp * 16;
            bf16x8 bh0 = *(const bf16x8*)(hb);
            bf16x8 bh1 = *(const bf16x8*)(hb + 64);

            // ---- per tile: 4 MFMA, all independent (1-deep chains) ----
            f32x4 acc[2];
#pragma unroll
            for (int tt = 0; tt < 2; ++tt) {
                if (!act[tt]) continue;
                f32x4 a0 = {0.f, 0.f, 0.f, 0.f};
                f32x4 a1 = {0.f, 0.f, 0.f, 0.f};
                f32x4 a2 = {0.f, 0.f, 0.f, 0.f};
                f32x4 a3 = {0.f, 0.f, 0.f, 0.f};
                a0 = __builtin_amdgcn_mfma_f32_16x16x32_bf16(awhi[tt][0], bh0, a0, 0, 0, 0);
                a1 = __builtin_amdgcn_mfma_f32_16x16x32_bf16(awhi[tt][1], bh1, a1, 0, 0, 0);
                a2 = __builtin_amdgcn_mfma_f32_16x16x32_bf16(awlo[tt][0], bh0, a2, 0, 0, 0);
                a3 = __builtin_amdgcn_mfma_f32_16x16x32_bf16(awlo[tt][1], bh1, a3, 0, 0, 0);
                acc[tt] = (a0 + a2) + (a1 + a3);
            }

            // ---- epilogue, SoA: all exp2 first (8 independent trans) ----
            float ei[2], ef[2], eg[2], eo[2];
#pragma unroll
            for (int tt = 0; tt < 2; ++tt) {
                if (!act[tt]) continue;
                ei[tt] = __builtin_amdgcn_exp2f(acc[tt][0]);
                ef[tt] = __builtin_amdgcn_exp2f(acc[tt][1]);
                eg[tt] = __builtin_amdgcn_exp2f(acc[tt][2]);
                eo[tt] = __builtin_amdgcn_exp2f(acc[tt][3]);
            }
#pragma unroll
            for (int tt = 0; tt < 2; ++tt) {
                if (!act[tt]) continue;
                const int u = (wvf * 2 + tt) * 4 + grp;
                // merged triple-product rcp: serves sigma(f) AND sig(i)*tanh(g)
                float pf = 1.0f + ef[tt];
                float pi = 1.0f + ei[tt];
                float pg = eg[tt] + 1.0f;
                float r  = __builtin_amdgcn_rcpf(pf * pi * pg);
                float sf    = r * (pi * pg);
                float ig_tg = (eg[tt] - 1.0f) * (r * pf);
                float c = sf * c2[tt] + ig_tg;
                c = fminf(fmaxf(c, -32.0f), 32.0f);
                c2[tt] = c;
                float ec = __builtin_amdgcn_exp2f(L2E2 * c);
                float h  = (ec - 1.0f) * __builtin_amdgcn_rcpf((1.0f + eo[tt]) * (ec + 1.0f));
                hreg[tt] = h;
                if (u < HID) {
                    unsigned hp = cvt_pk_bf16(h, h);
                    *(short*)(db + col * RS + u * 2) = (short)(hp & 0xFFFFu);
                }
            }
        }

        // ---- x(t+1) into next buffer; prefetch x(t+2) ----
        if (xwriter) {
            unsigned xh = cvt_pk_bf16(xpre.x, xpre.y);
            float f0 = __uint_as_float(xh << 16);
            float f1 = __uint_as_float(xh & 0xFFFF0000u);
            unsigned xl = cvt_pk_bf16(xpre.x - f0, xpre.y - f1);
            *(unsigned*)(db + lane * RS + 100) = xh;
            *(unsigned*)(db + lane * RS + 104) = xl;
            int t2 = (t + 2 < T_STEPS) ? t + 2 : T_STEPS - 1;
            xpre = *(const float2*)(xptr + (size_t)t2 * 2);
        }

        pb ^= 1;
        __syncthreads();
    }

    // ---- final FC from fp32 h regs ----
    float* hf = (float*)(arena + HF_OFF);   // [16][64]
#pragma unroll
    for (int tt = 0; tt < 2; ++tt) {
        if (!act[tt]) continue;
        const int u = (wvf * 2 + tt) * 4 + grp;
        if (u < HID) hf[col * 64 + u] = hreg[tt];
    }
    __syncthreads();
    if (tid < ROWS * 3) {
        int m = tid / 3, o = tid - m * 3;
        float s = b_fc[o];
        for (int k = 0; k < HID; ++k)
            s += hf[m * 64 + k] * W_fc[o * HID + k];
        out[(size_t)(b0 + m) * 3 + o] = s;
    }
}

extern "C" void kernel_launch(void* const* d_in, const int* in_sizes, int n_in,
                              void* d_out, int out_size, void* d_ws, size_t ws_size,
                              hipStream_t stream) {
    const float* x    = (const float*)d_in[0];
    const float* W_ih = (const float*)d_in[1];
    const float* W_hh = (const float*)d_in[2];
    const float* b_ih = (const float*)d_in[3];
    const float* b_hh = (const float*)d_in[4];
    const float* W_fc = (const float*)d_in[5];
    const float* b_fc = (const float*)d_in[6];
    float* out = (float*)d_out;

    dim3 grid(4096 / ROWS);   // 256 blocks -> 1 per CU
    dim3 block(NTHREADS);     // 8 waves (7 compute + 1 x-writer)
    lstm_mfma11_kernel<<<grid, block, 0, stream>>>(x, W_ih, W_hh, b_ih, b_hh,
                                                   W_fc, b_fc, out);
}

// Round 16
// 290.272 us; speedup vs baseline: 1.0868x; 1.0868x over previous
//
#include <hip/hip_runtime.h>

// LSTM B=4096, T=512, I=2, H=50, O=3 — MFMA, round 16.
// Base = r13 loop body (best, 273us) + r14's "zero VM ops in t-loop" with the
// bank-conflict bug FIXED:
//  * x staged once to LDS as bf16 pairs at xs[t*17 + row] (stride-17 dwords:
//    staging writes cycle all 32 banks; loop reads hit 16 consecutive banks,
//    4-way broadcast within col groups -> conflict-free). r14's [row][t]
//    layout put all 16 cols in bank 0 (16-way conflict each t, +1.35e7).
//  * 7 waves (448 thr), no x-writer wave, no global loads or vmcnt drain in
//    the t-loop; grp==3 lanes substitute x(t) into reg0 of kt=1 B-frag.
// K map: k<50 h(bf16), 50 bias (B=1.0), 56/57 x0/x1 (bf16-hi), else 0.
//   A (M) = scaled weight rows (hi/lo VGPR frags), m=col: u=tau*4+(col>>2),
//   gate=col&3;  B (N) = h/x/bias, n-col = batch row (2x ds_read_b128).
//   C: col=lane&15=batch, grp=lane>>4=unit-in-tile, reg=GATE.
// ONE barrier per t; double-buffered h planes; exp2-direct merged-rcp epilogue.

typedef short bf16x8 __attribute__((ext_vector_type(8)));
typedef float f32x4  __attribute__((ext_vector_type(4)));

#define T_STEPS 512
#define HID     50
#define ROWS    16
#define RS      144                        // bytes per m-row (9 granules)
#define HBUF_SZ (ROWS * RS)                // 2304 B
#define XSTRIDE 17                         // dwords per t-slot (bank spread)
#define XS_OFF  (2 * HBUF_SZ)              // 4608 B
#define XS_SZ   (T_STEPS * XSTRIDE * 4)    // 34816 B
#define HF_OFF  (XS_OFF + XS_SZ)           // 39424 B
#define ARENA_SZ (HF_OFF + ROWS * 64 * 4)  // 43520 B
#define NTHREADS 448

#define L2E  1.442695040888963f
#define L2E2 2.885390081777927f

// init-time RTN bf16 hi/lo split (lo short = hi(f), hi short = residual)
__device__ __forceinline__ unsigned pack_hilo(float f) {
    unsigned u  = __float_as_uint(f);
    unsigned hi = (u + 0x7fffu + ((u >> 16) & 1u)) >> 16;
    float    fh = __uint_as_float(hi << 16);
    float    rl = f - fh;
    unsigned ul = __float_as_uint(rl);
    unsigned lo = (ul + 0x7fffu + ((ul >> 16) & 1u)) >> 16;
    return (hi & 0xFFFFu) | (lo << 16);
}
// 1-instr packed bf16 RNE: low short = bf16(a), high short = bf16(b)
__device__ __forceinline__ unsigned cvt_pk_bf16(float a, float b) {
    unsigned r;
    asm("v_cvt_pk_bf16_f32 %0, %1, %2" : "=v"(r) : "v"(a), "v"(b));
    return r;
}

__global__ __launch_bounds__(NTHREADS) void lstm_mfma12_kernel(
    const float* __restrict__ x,     // [B,T,2]
    const float* __restrict__ W_ih,  // [200,2]
    const float* __restrict__ W_hh,  // [200,50]
    const float* __restrict__ b_ih,  // [200]
    const float* __restrict__ b_hh,  // [200]
    const float* __restrict__ W_fc,  // [3,50]
    const float* __restrict__ b_fc,  // [3]
    float* __restrict__ out)         // [B,3]
{
    __shared__ __align__(16) char arena[ARENA_SZ];

    const int tid  = threadIdx.x;
    const int lane = tid & 63;
    const int wvf  = tid >> 6;         // wave 0..6 (all compute)
    const int col  = lane & 15;        // C col = batch row; A row index m
    const int grp  = lane >> 4;        // k-group; C row-group = unit-in-tile
    const int b0   = blockIdx.x * ROWS;

    // ---- zero h buffers + hf (xstage region fully overwritten) ----
    for (int i = tid; i < XS_OFF / 4; i += NTHREADS) ((int*)arena)[i] = 0;
    for (int i = tid; i < (ARENA_SZ - HF_OFF) / 4; i += NTHREADS)
        ((int*)(arena + HF_OFF))[i] = 0;

    // ---- stage x -> LDS bf16 pairs, TRANSPOSED: xs[t*17 + row] ----
    {
        unsigned* xs = (unsigned*)(arena + XS_OFF);
        for (int idx = tid; idx < ROWS * T_STEPS; idx += NTHREADS) {
            int row = idx >> 9;          // idx = row*512 + t (coalesced reads)
            int t   = idx & (T_STEPS - 1);
            float2 v = *(const float2*)(x + (size_t)(b0 + row) * (T_STEPS * 2) + t * 2);
            xs[t * XSTRIDE + row] = cvt_pk_bf16(v.x, v.y);
        }
    }

    // ---- A-frags (scaled weights, hi/lo) for tiles tau = 2*wvf + tt ----
    bf16x8 awhi[2][2], awlo[2][2];   // [tt][kt]
    bool act[2];
#pragma unroll
    for (int tt = 0; tt < 2; ++tt) {
        const int tau = wvf * 2 + tt;
        act[tt] = (tau * 4) < HID;
        const int u = tau * 4 + (col >> 2);
        const int g = col & 3;
        const float s = (g == 2) ? L2E2 : -L2E;   // fold gate scale into A
#pragma unroll
        for (int kt = 0; kt < 2; ++kt) {
            bf16x8 H, L;
#pragma unroll
            for (int e = 0; e < 8; ++e) {
                int k = kt * 32 + grp * 8 + e;
                float v = 0.f;
                if (act[tt] && u < HID) {
                    int j = g * HID + u;
                    if      (k < HID)  v = W_hh[j * HID + k];
                    else if (k == 50)  v = b_ih[j] + b_hh[j];   // bias slot
                    else if (k == 56)  v = W_ih[2 * j + 0];     // x0 slot
                    else if (k == 57)  v = W_ih[2 * j + 1];     // x1 slot
                }
                unsigned p = pack_hilo(v * s);
                H[e] = (short)(p & 0xFFFFu);
                L[e] = (short)(p >> 16);
            }
            awhi[tt][kt] = H;
            awlo[tt][kt] = L;
        }
    }

    __syncthreads();   // zeroing + xstage complete

    // bias multiplier: B-value 1.0 at k=50 (granule 6, byte 100), both buffers
    if (tid < 2 * ROWS) {
        int buf = tid >> 4, m = tid & 15;
        *(short*)(arena + buf * HBUF_SZ + m * RS + 100) = (short)0x3F80;
    }

    float c2[2]   = {0.f, 0.f};
    float hreg[2] = {0.f, 0.f};
    const bool isg3 = (grp == 3);
    const unsigned* xs = (const unsigned*)(arena + XS_OFF);

    __syncthreads();

    int pb = 0;
    for (int t = 0; t < T_STEPS; ++t) {
        char* db = arena + (pb ^ 1) * HBUF_SZ;

        // ---- B-frags: 2x ds_read_b128 + 1 broadcast ds_read_b32 (x) ----
        const char* hb = arena + pb * HBUF_SZ + col * RS + grp * 16;
        bf16x8 bh0 = *(const bf16x8*)(hb);
        union { unsigned d[4]; bf16x8 v; } B1;
        B1.v = *(const bf16x8*)(hb + 64);
        unsigned xv = xs[t * XSTRIDE + col];
        if (isg3) B1.d[0] = xv;          // k=56/57 slots <- x(t) (one cndmask)
        bf16x8 bh1 = B1.v;

        // ---- per tile: 4 MFMA in two independent 2-chains (r13 form) ----
        f32x4 acc[2];
#pragma unroll
        for (int tt = 0; tt < 2; ++tt) {
            if (!act[tt]) continue;
            f32x4 a0 = {0.f, 0.f, 0.f, 0.f};
            f32x4 a1 = {0.f, 0.f, 0.f, 0.f};
            a0 = __builtin_amdgcn_mfma_f32_16x16x32_bf16(awhi[tt][0], bh0, a0, 0, 0, 0);
            a1 = __builtin_amdgcn_mfma_f32_16x16x32_bf16(awhi[tt][1], bh1, a1, 0, 0, 0);
            a0 = __builtin_amdgcn_mfma_f32_16x16x32_bf16(awlo[tt][0], bh0, a0, 0, 0, 0);
            a1 = __builtin_amdgcn_mfma_f32_16x16x32_bf16(awlo[tt][1], bh1, a1, 0, 0, 0);
            acc[tt] = a0 + a1;
        }

        // ---- epilogue (r13 form): exp2-direct, merged rcp ----
#pragma unroll
        for (int tt = 0; tt < 2; ++tt) {
            if (!act[tt]) continue;
            const int u = (wvf * 2 + tt) * 4 + grp;
            float ei = __builtin_amdgcn_exp2f(acc[tt][0]);
            float ef = __builtin_amdgcn_exp2f(acc[tt][1]);
            float eg = __builtin_amdgcn_exp2f(acc[tt][2]);
            float eo = __builtin_amdgcn_exp2f(acc[tt][3]);
            float sf    = __builtin_amdgcn_rcpf(1.0f + ef);
            float ig_tg = (eg - 1.0f) * __builtin_amdgcn_rcpf((1.0f + ei) * (eg + 1.0f));
            float c = sf * c2[tt] + ig_tg;
            c = fminf(fmaxf(c, -32.0f), 32.0f);
            c2[tt] = c;
            float ec = __builtin_amdgcn_exp2f(L2E2 * c);
            float h  = (ec - 1.0f) * __builtin_amdgcn_rcpf((1.0f + eo) * (ec + 1.0f));
            hreg[tt] = h;
            if (u < HID) {
                unsigned hp = cvt_pk_bf16(h, h);
                *(short*)(db + col * RS + u * 2) = (short)(hp & 0xFFFFu);
            }
        }

        pb ^= 1;
        __syncthreads();
    }

    // ---- final FC from fp32 h regs ----
    float* hf = (float*)(arena + HF_OFF);   // [16][64]
#pragma unroll
    for (int tt = 0; tt < 2; ++tt) {
        if (!act[tt]) continue;
        const int u = (wvf * 2 + tt) * 4 + grp;
        if (u < HID) hf[col * 64 + u] = hreg[tt];
    }
    __syncthreads();
    if (tid < ROWS * 3) {
        int m = tid / 3, o = tid - m * 3;
        float s = b_fc[o];
        for (int k = 0; k < HID; ++k)
            s += hf[m * 64 + k] * W_fc[o * HID + k];
        out[(size_t)(b0 + m) * 3 + o] = s;
    }
}

extern "C" void kernel_launch(void* const* d_in, const int* in_sizes, int n_in,
                              void* d_out, int out_size, void* d_ws, size_t ws_size,
                              hipStream_t stream) {
    const float* x    = (const float*)d_in[0];
    const float* W_ih = (const float*)d_in[1];
    const float* W_hh = (const float*)d_in[2];
    const float* b_ih = (const float*)d_in[3];
    const float* b_hh = (const float*)d_in[4];
    const float* W_fc = (const float*)d_in[5];
    const float* b_fc = (const float*)d_in[6];
    float* out = (float*)d_out;

    dim3 grid(4096 / ROWS);   // 256 blocks -> 1 per CU
    dim3 block(NTHREADS);     // 7 waves, all compute
    lstm_mfma12_kernel<<<grid, block, 0, stream>>>(x, W_ih, W_hh, b_ih, b_hh,
                                                   W_fc, b_fc, out);
}

// Round 17
// 276.711 us; speedup vs baseline: 1.1401x; 1.0490x over previous
//
#include <hip/hip_runtime.h>

// LSTM B=4096, T=512, I=2, H=50, O=3 — MFMA, round 17.
// = r13's proven loop body + r16's "zero VM ops in t-loop", with r16's
// 7-wave asymmetry FIXED: 8 waves (512 thr), 2 per SIMD on every SIMD, all
// executing the IDENTICAL instruction stream (wave 6 tile-slot 1 and wave 7
// compute on zero pad weights; only h-writes are masked by u<HID) ->
// symmetric barrier arrival, no straggler SIMD.
//  * x staged once to LDS bf16 pairs at xs[t*17 + col] (conflict-free
//    broadcast read); grp==3 lanes cndmask x(t) into reg0 of kt=1 B-frag.
//  * no global loads / vmcnt drains inside the t-loop (lgkmcnt only).
// K map: k<50 h(bf16), 50 bias (B=1.0 slot), 56/57 x0/x1 (bf16-hi), else 0.
//   A (M) = scaled weight rows (hi/lo VGPR frags), m=col: u=tau*4+(col>>2),
//   gate=col&3;  B (N) = h/x/bias, n-col = batch row (2x ds_read_b128).
//   C: col=lane&15=batch, grp=lane>>4=unit-in-tile, reg=GATE.
// ONE barrier per t; double-buffered h planes; exp2-direct merged-rcp epilogue.

typedef short bf16x8 __attribute__((ext_vector_type(8)));
typedef float f32x4  __attribute__((ext_vector_type(4)));

#define T_STEPS 512
#define HID     50
#define ROWS    16
#define RS      144                        // bytes per m-row (9 granules)
#define HBUF_SZ (ROWS * RS)                // 2304 B
#define XSTRIDE 17                         // dwords per t-slot (bank spread)
#define XS_OFF  (2 * HBUF_SZ)              // 4608 B
#define XS_SZ   (T_STEPS * XSTRIDE * 4)    // 34816 B
#define HF_OFF  (XS_OFF + XS_SZ)           // 39424 B
#define ARENA_SZ (HF_OFF + ROWS * 64 * 4)  // 43520 B
#define NTHREADS 512

#define L2E  1.442695040888963f
#define L2E2 2.885390081777927f

// init-time RTN bf16 hi/lo split (lo short = hi(f), hi short = residual)
__device__ __forceinline__ unsigned pack_hilo(float f) {
    unsigned u  = __float_as_uint(f);
    unsigned hi = (u + 0x7fffu + ((u >> 16) & 1u)) >> 16;
    float    fh = __uint_as_float(hi << 16);
    float    rl = f - fh;
    unsigned ul = __float_as_uint(rl);
    unsigned lo = (ul + 0x7fffu + ((ul >> 16) & 1u)) >> 16;
    return (hi & 0xFFFFu) | (lo << 16);
}
// 1-instr packed bf16 RNE: low short = bf16(a), high short = bf16(b)
__device__ __forceinline__ unsigned cvt_pk_bf16(float a, float b) {
    unsigned r;
    asm("v_cvt_pk_bf16_f32 %0, %1, %2" : "=v"(r) : "v"(a), "v"(b));
    return r;
}

__global__ __launch_bounds__(NTHREADS) void lstm_mfma13_kernel(
    const float* __restrict__ x,     // [B,T,2]
    const float* __restrict__ W_ih,  // [200,2]
    const float* __restrict__ W_hh,  // [200,50]
    const float* __restrict__ b_ih,  // [200]
    const float* __restrict__ b_hh,  // [200]
    const float* __restrict__ W_fc,  // [3,50]
    const float* __restrict__ b_fc,  // [3]
    float* __restrict__ out)         // [B,3]
{
    __shared__ __align__(16) char arena[ARENA_SZ];

    const int tid  = threadIdx.x;
    const int lane = tid & 63;
    const int wvf  = tid >> 6;         // wave 0..7, all identical work
    const int col  = lane & 15;        // C col = batch row; A row index m
    const int grp  = lane >> 4;        // k-group; C row-group = unit-in-tile
    const int b0   = blockIdx.x * ROWS;

    // ---- zero h buffers + hf (xstage region fully overwritten) ----
    for (int i = tid; i < XS_OFF / 4; i += NTHREADS) ((int*)arena)[i] = 0;
    for (int i = tid; i < (ARENA_SZ - HF_OFF) / 4; i += NTHREADS)
        ((int*)(arena + HF_OFF))[i] = 0;

    // ---- stage x -> LDS bf16 pairs, transposed: xs[t*17 + row] ----
    {
        unsigned* xs = (unsigned*)(arena + XS_OFF);
        for (int idx = tid; idx < ROWS * T_STEPS; idx += NTHREADS) {
            int row = idx >> 9;          // idx = row*512 + t (coalesced reads)
            int t   = idx & (T_STEPS - 1);
            float2 v = *(const float2*)(x + (size_t)(b0 + row) * (T_STEPS * 2) + t * 2);
            xs[t * XSTRIDE + row] = cvt_pk_bf16(v.x, v.y);
        }
    }

    // ---- A-frags (scaled weights, hi/lo) for tiles tau = 2*wvf + tt ----
    // Pad tiles (tau >= 13) get zero weights but execute identically.
    bf16x8 awhi[2][2], awlo[2][2];   // [tt][kt]
#pragma unroll
    for (int tt = 0; tt < 2; ++tt) {
        const int tau = wvf * 2 + tt;
        const int u = tau * 4 + (col >> 2);
        const int g = col & 3;
        const float s = (g == 2) ? L2E2 : -L2E;   // fold gate scale into A
#pragma unroll
        for (int kt = 0; kt < 2; ++kt) {
            bf16x8 H, L;
#pragma unroll
            for (int e = 0; e < 8; ++e) {
                int k = kt * 32 + grp * 8 + e;
                float v = 0.f;
                if (u < HID) {
                    int j = g * HID + u;
                    if      (k < HID)  v = W_hh[j * HID + k];
                    else if (k == 50)  v = b_ih[j] + b_hh[j];   // bias slot
                    else if (k == 56)  v = W_ih[2 * j + 0];     // x0 slot
                    else if (k == 57)  v = W_ih[2 * j + 1];     // x1 slot
                }
                unsigned p = pack_hilo(v * s);
                H[e] = (short)(p & 0xFFFFu);
                L[e] = (short)(p >> 16);
            }
            awhi[tt][kt] = H;
            awlo[tt][kt] = L;
        }
    }

    __syncthreads();   // zeroing + xstage complete

    // bias multiplier: B-value 1.0 at k=50 (granule 6, byte 100), both buffers
    if (tid < 2 * ROWS) {
        int buf = tid >> 4, m = tid & 15;
        *(short*)(arena + buf * HBUF_SZ + m * RS + 100) = (short)0x3F80;
    }

    float c2[2]   = {0.f, 0.f};
    float hreg[2] = {0.f, 0.f};
    const bool isg3 = (grp == 3);
    const unsigned* xs = (const unsigned*)(arena + XS_OFF);

    __syncthreads();

    int pb = 0;
    for (int t = 0; t < T_STEPS; ++t) {
        char* db = arena + (pb ^ 1) * HBUF_SZ;

        // ---- B-frags: 2x ds_read_b128 + 1 broadcast ds_read_b32 (x) ----
        const char* hb = arena + pb * HBUF_SZ + col * RS + grp * 16;
        bf16x8 bh0 = *(const bf16x8*)(hb);
        union { unsigned d[4]; bf16x8 v; } B1;
        B1.v = *(const bf16x8*)(hb + 64);
        unsigned xv = xs[t * XSTRIDE + col];
        if (isg3) B1.d[0] = xv;          // k=56/57 slots <- x(t) (one cndmask)
        bf16x8 bh1 = B1.v;

        // ---- per tile: 4 MFMA in two independent 2-chains (r13 form) ----
        f32x4 acc[2];
#pragma unroll
        for (int tt = 0; tt < 2; ++tt) {
            f32x4 a0 = {0.f, 0.f, 0.f, 0.f};
            f32x4 a1 = {0.f, 0.f, 0.f, 0.f};
            a0 = __builtin_amdgcn_mfma_f32_16x16x32_bf16(awhi[tt][0], bh0, a0, 0, 0, 0);
            a1 = __builtin_amdgcn_mfma_f32_16x16x32_bf16(awhi[tt][1], bh1, a1, 0, 0, 0);
            a0 = __builtin_amdgcn_mfma_f32_16x16x32_bf16(awlo[tt][0], bh0, a0, 0, 0, 0);
            a1 = __builtin_amdgcn_mfma_f32_16x16x32_bf16(awlo[tt][1], bh1, a1, 0, 0, 0);
            acc[tt] = a0 + a1;
        }

        // ---- epilogue (r13 form): exp2-direct, merged rcp; writes masked ----
#pragma unroll
        for (int tt = 0; tt < 2; ++tt) {
            const int u = (wvf * 2 + tt) * 4 + grp;
            float ei = __builtin_amdgcn_exp2f(acc[tt][0]);
            float ef = __builtin_amdgcn_exp2f(acc[tt][1]);
            float eg = __builtin_amdgcn_exp2f(acc[tt][2]);
            float eo = __builtin_amdgcn_exp2f(acc[tt][3]);
            float sf    = __builtin_amdgcn_rcpf(1.0f + ef);
            float ig_tg = (eg - 1.0f) * __builtin_amdgcn_rcpf((1.0f + ei) * (eg + 1.0f));
            float c = sf * c2[tt] + ig_tg;
            c = fminf(fmaxf(c, -32.0f), 32.0f);
            c2[tt] = c;
            float ec = __builtin_amdgcn_exp2f(L2E2 * c);
            float h  = (ec - 1.0f) * __builtin_amdgcn_rcpf((1.0f + eo) * (ec + 1.0f));
            hreg[tt] = h;
            if (u < HID) {
                unsigned hp = cvt_pk_bf16(h, h);
                *(short*)(db + col * RS + u * 2) = (short)(hp & 0xFFFFu);
            }
        }

        pb ^= 1;
        __syncthreads();
    }

    // ---- final FC from fp32 h regs ----
    float* hf = (float*)(arena + HF_OFF);   // [16][64]
#pragma unroll
    for (int tt = 0; tt < 2; ++tt) {
        const int u = (wvf * 2 + tt) * 4 + grp;
        if (u < HID) hf[col * 64 + u] = hreg[tt];
    }
    __syncthreads();
    if (tid < ROWS * 3) {
        int m = tid / 3, o = tid - m * 3;
        float s = b_fc[o];
        for (int k = 0; k < HID; ++k)
            s += hf[m * 64 + k] * W_fc[o * HID + k];
        out[(size_t)(b0 + m) * 3 + o] = s;
    }
}

extern "C" void kernel_launch(void* const* d_in, const int* in_sizes, int n_in,
                              void* d_out, int out_size, void* d_ws, size_t ws_size,
                              hipStream_t stream) {
    const float* x    = (const float*)d_in[0];
    const float* W_ih = (const float*)d_in[1];
    const float* W_hh = (const float*)d_in[2];
    const float* b_ih = (const float*)d_in[3];
    const float* b_hh = (const float*)d_in[4];
    const float* W_fc = (const float*)d_in[5];
    const float* b_fc = (const float*)d_in[6];
    float* out = (float*)d_out;

    dim3 grid(4096 / ROWS);   // 256 blocks -> 1 per CU
    dim3 block(NTHREADS);     // 8 waves, 2/SIMD on every SIMD, all symmetric
    lstm_mfma13_kernel<<<grid, block, 0, stream>>>(x, W_ih, W_hh, b_ih, b_hh,
                                                   W_fc, b_fc, out);
}

// Round 18
// 241.608 us; speedup vs baseline: 1.3057x; 1.1453x over previous
//
#include <hip/hip_runtime.h>

// LSTM B=4096, T=512, I=2, H=50, O=3 — MFMA, round 18.
// = r13 (best, 273us) minus issued ops (regime proven by r10/r12/r17: wall =
// lockstep SUM of pipe issue cycles; only op-count reductions move it):
//  1. all 4 MFMAs per tile chained through the C operand (accumulation
//     chaining is the cheap designed path) -> the a0+a1 f32x4 add is gone.
//  2. cell state kept pre-scaled: c' = 2log2(e)*c. Saves the L2E2*c mul
//     before exp2; (eg-1) -> fma(eg,L2E2,-L2E2) (same count); clamp is
//     UPPER-only (exp2(-big)=0 gives the exact tanh(-inf) limit = more
//     accurate than r13's lower clamp).
//  3. t-loop unrolled x2 with static double-buffer pointers (no pb flip,
//     no per-iter pointer selects).
// Everything else identical to r13: 8 waves (7 compute x 2 tiles + wave-7
// x-writer), RS=144, h plain bf16, K map k<50 h, 50/51 x-hi, 52/53 x-lo,
// 54 bias (B=1.0), scale-folded A-frags, ONE barrier per t.

typedef short bf16x8 __attribute__((ext_vector_type(8)));
typedef float f32x4  __attribute__((ext_vector_type(4)));

#define T_STEPS 512
#define HID     50
#define ROWS    16
#define RS      144                        // bytes per m-row (9 granules)
#define HBUF_SZ (ROWS * RS)                // 2304 B
#define HF_OFF  (2 * HBUF_SZ)              // 4608 B
#define ARENA_SZ (HF_OFF + ROWS * 64 * 4)  // 8704 B
#define NTHREADS 512

#define L2E  1.442695040888963f
#define L2E2 2.885390081777927f

// init-time RTN bf16 hi/lo split (lo short = hi(f), hi short = residual)
__device__ __forceinline__ unsigned pack_hilo(float f) {
    unsigned u  = __float_as_uint(f);
    unsigned hi = (u + 0x7fffu + ((u >> 16) & 1u)) >> 16;
    float    fh = __uint_as_float(hi << 16);
    float    rl = f - fh;
    unsigned ul = __float_as_uint(rl);
    unsigned lo = (ul + 0x7fffu + ((ul >> 16) & 1u)) >> 16;
    return (hi & 0xFFFFu) | (lo << 16);
}
// 1-instr packed bf16 RNE: low short = bf16(a), high short = bf16(b)
__device__ __forceinline__ unsigned cvt_pk_bf16(float a, float b) {
    unsigned r;
    asm("v_cvt_pk_bf16_f32 %0, %1, %2" : "=v"(r) : "v"(a), "v"(b));
    return r;
}

__global__ __launch_bounds__(NTHREADS) void lstm_mfma14_kernel(
    const float* __restrict__ x,     // [B,T,2]
    const float* __restrict__ W_ih,  // [200,2]
    const float* __restrict__ W_hh,  // [200,50]
    const float* __restrict__ b_ih,  // [200]
    const float* __restrict__ b_hh,  // [200]
    const float* __restrict__ W_fc,  // [3,50]
    const float* __restrict__ b_fc,  // [3]
    float* __restrict__ out)         // [B,3]
{
    __shared__ __align__(16) char arena[ARENA_SZ];

    const int tid  = threadIdx.x;
    const int lane = tid & 63;
    const int wvf  = tid >> 6;         // wave 0..7
    const int col  = lane & 15;        // C col = batch row; A row index m
    const int grp  = lane >> 4;        // k-group; C row-group = unit-in-tile
    const int b0   = blockIdx.x * ROWS;

    // ---- zero arena ----
    for (int i = tid; i < ARENA_SZ / 4; i += NTHREADS) ((int*)arena)[i] = 0;

    // ---- A-frags (scaled weights, hi/lo) for tiles tau = 2*wvf + tt ----
    bf16x8 awhi[2][2], awlo[2][2];   // [tt][kt]
    bool act[2];
#pragma unroll
    for (int tt = 0; tt < 2; ++tt) {
        const int tau = wvf * 2 + tt;
        act[tt] = (wvf < 7) && (tau * 4 < HID);
        const int u = tau * 4 + (col >> 2);
        const int g = col & 3;
        const float s = (g == 2) ? L2E2 : -L2E;   // fold gate scale into W
#pragma unroll
        for (int kt = 0; kt < 2; ++kt) {
            bf16x8 H, L;
#pragma unroll
            for (int e = 0; e < 8; ++e) {
                int k = kt * 32 + grp * 8 + e;
                float v = 0.f;
                if (act[tt] && u < HID) {
                    int j = g * HID + u;
                    if      (k < HID)  v = W_hh[j * HID + k];
                    else if (k == 50 || k == 52)  v = W_ih[2 * j + 0];
                    else if (k == 51 || k == 53)  v = W_ih[2 * j + 1];
                    else if (k == 54)  v = b_ih[j] + b_hh[j];
                }
                unsigned p = pack_hilo(v * s);
                H[e] = (short)(p & 0xFFFFu);
                L[e] = (short)(p >> 16);
            }
            awhi[tt][kt] = H;
            awlo[tt][kt] = L;
        }
    }

    __syncthreads();   // zeroing complete

    // const-1.0 at k=54 (byte 108), both buffers (bias multiplier)
    if (tid < 2 * ROWS) {
        int buf = tid >> 4, m = tid & 15;
        *(short*)(arena + buf * HBUF_SZ + m * RS + 108) = (short)0x3F80;
    }
    // x writer: wave 7, lanes 0..15 (lane = batch row)
    const bool xwriter = (wvf == 7) && (lane < 16);
    const float* xptr = x + (size_t)(b0 + lane) * (T_STEPS * 2);
    if (xwriter) {   // x(t=0) into buffer 0: hi at bytes 100..103, lo 104..107
        float2 xv = *(const float2*)xptr;
        unsigned xh = cvt_pk_bf16(xv.x, xv.y);
        float f0 = __uint_as_float(xh << 16);
        float f1 = __uint_as_float(xh & 0xFFFF0000u);
        unsigned xl = cvt_pk_bf16(xv.x - f0, xv.y - f1);
        *(unsigned*)(arena + lane * RS + 100) = xh;
        *(unsigned*)(arena + lane * RS + 104) = xl;
    }
    float2 xpre = xwriter ? *(const float2*)(xptr + 2) : make_float2(0.f, 0.f);

    float cp[2]   = {0.f, 0.f};    // c' = L2E2 * c (pre-scaled cell state)
    float hreg[2] = {0.f, 0.f};

    __syncthreads();

    // ---- one timestep: read rb, write db (static pointers via unroll) ----
    auto STEP = [&](const char* rb, char* db, int t) {
        if (wvf < 7) {
            const char* hb = rb + col * RS + grp * 16;
            bf16x8 bh0 = *(const bf16x8*)(hb);
            bf16x8 bh1 = *(const bf16x8*)(hb + 64);

            f32x4 acc[2];
#pragma unroll
            for (int tt = 0; tt < 2; ++tt) {
                if (!act[tt]) continue;
                f32x4 a = {0.f, 0.f, 0.f, 0.f};   // all 4 chained through C
                a = __builtin_amdgcn_mfma_f32_16x16x32_bf16(awhi[tt][0], bh0, a, 0, 0, 0);
                a = __builtin_amdgcn_mfma_f32_16x16x32_bf16(awhi[tt][1], bh1, a, 0, 0, 0);
                a = __builtin_amdgcn_mfma_f32_16x16x32_bf16(awlo[tt][0], bh0, a, 0, 0, 0);
                a = __builtin_amdgcn_mfma_f32_16x16x32_bf16(awlo[tt][1], bh1, a, 0, 0, 0);
                acc[tt] = a;
            }

#pragma unroll
            for (int tt = 0; tt < 2; ++tt) {
                if (!act[tt]) continue;
                const int u = (wvf * 2 + tt) * 4 + grp;
                float ei = __builtin_amdgcn_exp2f(acc[tt][0]);
                float ef = __builtin_amdgcn_exp2f(acc[tt][1]);
                float eg = __builtin_amdgcn_exp2f(acc[tt][2]);
                float eo = __builtin_amdgcn_exp2f(acc[tt][3]);
                float sf = __builtin_amdgcn_rcpf(1.0f + ef);
                float r  = __builtin_amdgcn_rcpf((1.0f + ei) * (eg + 1.0f));
                float t5 = fmaf(eg, L2E2, -L2E2);     // L2E2*(eg-1)
                float c  = fmaf(sf, cp[tt], t5 * r);  // c' = sf*c' + L2E2*ig_tg
                c = fminf(c, 92.0f);                  // upper clamp only
                cp[tt] = c;
                float ec = __builtin_amdgcn_exp2f(c); // = e^{2c_true}
                float h  = (ec - 1.0f) * __builtin_amdgcn_rcpf((1.0f + eo) * (ec + 1.0f));
                hreg[tt] = h;
                if (u < HID) {
                    unsigned hp = cvt_pk_bf16(h, h);
                    *(short*)(db + col * RS + u * 2) = (short)(hp & 0xFFFFu);
                }
            }
        }

        if (xwriter) {
            unsigned xh = cvt_pk_bf16(xpre.x, xpre.y);
            float f0 = __uint_as_float(xh << 16);
            float f1 = __uint_as_float(xh & 0xFFFF0000u);
            unsigned xl = cvt_pk_bf16(xpre.x - f0, xpre.y - f1);
            *(unsigned*)(db + lane * RS + 100) = xh;
            *(unsigned*)(db + lane * RS + 104) = xl;
            int t2 = (t + 2 < T_STEPS) ? t + 2 : T_STEPS - 1;
            xpre = *(const float2*)(xptr + (size_t)t2 * 2);
        }

        __syncthreads();
    };

    char* bufA = arena;
    char* bufB = arena + HBUF_SZ;
    for (int t = 0; t < T_STEPS; t += 2) {
        STEP(bufA, bufB, t);
        STEP(bufB, bufA, t + 1);
    }

    // ---- final FC from fp32 h regs ----
    float* hf = (float*)(arena + HF_OFF);   // [16][64]
#pragma unroll
    for (int tt = 0; tt < 2; ++tt) {
        if (!act[tt]) continue;
        const int u = (wvf * 2 + tt) * 4 + grp;
        if (u < HID) hf[col * 64 + u] = hreg[tt];
    }
    __syncthreads();
    if (tid < ROWS * 3) {
        int m = tid / 3, o = tid - m * 3;
        float s = b_fc[o];
        for (int k = 0; k < HID; ++k)
            s += hf[m * 64 + k] * W_fc[o * HID + k];
        out[(size_t)(b0 + m) * 3 + o] = s;
    }
}

extern "C" void kernel_launch(void* const* d_in, const int* in_sizes, int n_in,
                              void* d_out, int out_size, void* d_ws, size_t ws_size,
                              hipStream_t stream) {
    const float* x    = (const float*)d_in[0];
    const float* W_ih = (const float*)d_in[1];
    const float* W_hh = (const float*)d_in[2];
    const float* b_ih = (const float*)d_in[3];
    const float* b_hh = (const float*)d_in[4];
    const float* W_fc = (const float*)d_in[5];
    const float* b_fc = (const float*)d_in[6];
    float* out = (float*)d_out;

    dim3 grid(4096 / ROWS);   // 256 blocks -> 1 per CU
    dim3 block(NTHREADS);     // 8 waves (7 compute + 1 x-writer)
    lstm_mfma14_kernel<<<grid, block, 0, stream>>>(x, W_ih, W_hh, b_ih, b_hh,
                                                   W_fc, b_fc, out);
}

// Round 19
// 217.191 us; speedup vs baseline: 1.4525x; 1.1124x over previous
//
#include <hip/hip_runtime.h>

// LSTM B=4096, T=512, I=2, H=50, O=3 — MFMA, round 19.
// = r18 (best, 241us) minus the W-lo MFMA plane: 2 MFMA/tile (was 4),
// A-frag regs halved, MFMA C-chain 2-deep (was 4).
// Precision kept surgically: ONLY W_hh degrades to plain bf16. The single
// A-plane's free K slots carry exact terms:
//   k 0..49 : W_hh (bf16-hi)            x  h (bf16)
//   k 50/51 : W_ih hi                   x  x0/x1 hi
//   k 52/53 : W_ih hi                   x  x0/x1 lo     [x exact]
//   k 54    : bias hi                   x  1.0
//   k 55    : bias lo                   x  1.0          [bias exact]
//   k 56/57 : W_ih lo                   x  x0/x1 hi     [W_ih exact 2nd order]
// x-writer (wave 7) writes xh at k50/51, xl at k52/53, xh again at k56/57.
// Everything else byte-identical to r18: 8 waves, RS=144, ONE barrier/t,
// exp2-direct pre-scaled-c' epilogue, static double-buffer unroll x2.

typedef short bf16x8 __attribute__((ext_vector_type(8)));
typedef float f32x4  __attribute__((ext_vector_type(4)));

#define T_STEPS 512
#define HID     50
#define ROWS    16
#define RS      144                        // bytes per m-row (9 granules)
#define HBUF_SZ (ROWS * RS)                // 2304 B
#define HF_OFF  (2 * HBUF_SZ)              // 4608 B
#define ARENA_SZ (HF_OFF + ROWS * 64 * 4)  // 8704 B
#define NTHREADS 512

#define L2E  1.442695040888963f
#define L2E2 2.885390081777927f

// init-time RTN bf16 hi/lo split (lo short = hi(f), hi short = residual)
__device__ __forceinline__ unsigned pack_hilo(float f) {
    unsigned u  = __float_as_uint(f);
    unsigned hi = (u + 0x7fffu + ((u >> 16) & 1u)) >> 16;
    float    fh = __uint_as_float(hi << 16);
    float    rl = f - fh;
    unsigned ul = __float_as_uint(rl);
    unsigned lo = (ul + 0x7fffu + ((ul >> 16) & 1u)) >> 16;
    return (hi & 0xFFFFu) | (lo << 16);
}
// 1-instr packed bf16 RNE: low short = bf16(a), high short = bf16(b)
__device__ __forceinline__ unsigned cvt_pk_bf16(float a, float b) {
    unsigned r;
    asm("v_cvt_pk_bf16_f32 %0, %1, %2" : "=v"(r) : "v"(a), "v"(b));
    return r;
}

__global__ __launch_bounds__(NTHREADS) void lstm_mfma15_kernel(
    const float* __restrict__ x,     // [B,T,2]
    const float* __restrict__ W_ih,  // [200,2]
    const float* __restrict__ W_hh,  // [200,50]
    const float* __restrict__ b_ih,  // [200]
    const float* __restrict__ b_hh,  // [200]
    const float* __restrict__ W_fc,  // [3,50]
    const float* __restrict__ b_fc,  // [3]
    float* __restrict__ out)         // [B,3]
{
    __shared__ __align__(16) char arena[ARENA_SZ];

    const int tid  = threadIdx.x;
    const int lane = tid & 63;
    const int wvf  = tid >> 6;         // wave 0..7
    const int col  = lane & 15;        // C col = batch row; A row index m
    const int grp  = lane >> 4;        // k-group; C row-group = unit-in-tile
    const int b0   = blockIdx.x * ROWS;

    // ---- zero arena ----
    for (int i = tid; i < ARENA_SZ / 4; i += NTHREADS) ((int*)arena)[i] = 0;

    // ---- A-frags (single plane, scaled) for tiles tau = 2*wvf + tt ----
    bf16x8 awf[2][2];   // [tt][kt]
    bool act[2];
#pragma unroll
    for (int tt = 0; tt < 2; ++tt) {
        const int tau = wvf * 2 + tt;
        act[tt] = (wvf < 7) && (tau * 4 < HID);
        const int u = tau * 4 + (col >> 2);
        const int g = col & 3;
        const float s = (g == 2) ? L2E2 : -L2E;   // fold gate scale into W
#pragma unroll
        for (int kt = 0; kt < 2; ++kt) {
            bf16x8 F;
#pragma unroll
            for (int e = 0; e < 8; ++e) {
                int k = kt * 32 + grp * 8 + e;
                float v = 0.f;
                int  mode = 0;   // 0=zero, 1=hi(v*s), 2=lo(v*s)
                if (act[tt] && u < HID) {
                    int j = g * HID + u;
                    if      (k < HID)  { v = W_hh[j * HID + k];     mode = 1; }
                    else if (k == 50 || k == 52) { v = W_ih[2*j+0]; mode = 1; }
                    else if (k == 51 || k == 53) { v = W_ih[2*j+1]; mode = 1; }
                    else if (k == 54)  { v = b_ih[j] + b_hh[j];     mode = 1; }
                    else if (k == 55)  { v = b_ih[j] + b_hh[j];     mode = 2; }
                    else if (k == 56)  { v = W_ih[2*j+0];           mode = 2; }
                    else if (k == 57)  { v = W_ih[2*j+1];           mode = 2; }
                }
                unsigned p = pack_hilo(v * s);
                F[e] = (mode == 2) ? (short)(p >> 16)
                                   : (mode == 1 ? (short)(p & 0xFFFFu) : (short)0);
            }
            awf[tt][kt] = F;
        }
    }

    __syncthreads();   // zeroing complete

    // bias multipliers: B = 1.0 at k=54 AND k=55 (bytes 108..111), both buffers
    if (tid < 2 * ROWS) {
        int buf = tid >> 4, m = tid & 15;
        *(unsigned*)(arena + buf * HBUF_SZ + m * RS + 108) = 0x3F803F80u;
    }
    // x writer: wave 7, lanes 0..15 (lane = batch row)
    const bool xwriter = (wvf == 7) && (lane < 16);
    const float* xptr = x + (size_t)(b0 + lane) * (T_STEPS * 2);
    if (xwriter) {   // x(t=0) into buffer 0
        float2 xv = *(const float2*)xptr;
        unsigned xh = cvt_pk_bf16(xv.x, xv.y);
        float f0 = __uint_as_float(xh << 16);
        float f1 = __uint_as_float(xh & 0xFFFF0000u);
        unsigned xl = cvt_pk_bf16(xv.x - f0, xv.y - f1);
        *(unsigned*)(arena + lane * RS + 100) = xh;   // k50/51 <- x hi
        *(unsigned*)(arena + lane * RS + 104) = xl;   // k52/53 <- x lo
        *(unsigned*)(arena + lane * RS + 112) = xh;   // k56/57 <- x hi (dup)
    }
    float2 xpre = xwriter ? *(const float2*)(xptr + 2) : make_float2(0.f, 0.f);

    float cp[2]   = {0.f, 0.f};    // c' = L2E2 * c (pre-scaled cell state)
    float hreg[2] = {0.f, 0.f};

    __syncthreads();

    // ---- one timestep: read rb, write db (static pointers via unroll) ----
    auto STEP = [&](const char* rb, char* db, int t) {
        if (wvf < 7) {
            const char* hb = rb + col * RS + grp * 16;
            bf16x8 bh0 = *(const bf16x8*)(hb);
            bf16x8 bh1 = *(const bf16x8*)(hb + 64);

            f32x4 acc[2];
#pragma unroll
            for (int tt = 0; tt < 2; ++tt) {
                if (!act[tt]) continue;
                f32x4 a = {0.f, 0.f, 0.f, 0.f};   // 2 MFMA chained through C
                a = __builtin_amdgcn_mfma_f32_16x16x32_bf16(awf[tt][0], bh0, a, 0, 0, 0);
                a = __builtin_amdgcn_mfma_f32_16x16x32_bf16(awf[tt][1], bh1, a, 0, 0, 0);
                acc[tt] = a;
            }

#pragma unroll
            for (int tt = 0; tt < 2; ++tt) {
                if (!act[tt]) continue;
                const int u = (wvf * 2 + tt) * 4 + grp;
                float ei = __builtin_amdgcn_exp2f(acc[tt][0]);
                float ef = __builtin_amdgcn_exp2f(acc[tt][1]);
                float eg = __builtin_amdgcn_exp2f(acc[tt][2]);
                float eo = __builtin_amdgcn_exp2f(acc[tt][3]);
                float sf = __builtin_amdgcn_rcpf(1.0f + ef);
                float r  = __builtin_amdgcn_rcpf((1.0f + ei) * (eg + 1.0f));
                float t5 = fmaf(eg, L2E2, -L2E2);     // L2E2*(eg-1)
                float c  = fmaf(sf, cp[tt], t5 * r);  // c' = sf*c' + L2E2*ig_tg
                c = fminf(c, 92.0f);                  // upper clamp only
                cp[tt] = c;
                float ec = __builtin_amdgcn_exp2f(c); // = e^{2c_true}
                float h  = (ec - 1.0f) * __builtin_amdgcn_rcpf((1.0f + eo) * (ec + 1.0f));
                hreg[tt] = h;
                if (u < HID) {
                    unsigned hp = cvt_pk_bf16(h, h);
                    *(short*)(db + col * RS + u * 2) = (short)(hp & 0xFFFFu);
                }
            }
        }

        if (xwriter) {
            unsigned xh = cvt_pk_bf16(xpre.x, xpre.y);
            float f0 = __uint_as_float(xh << 16);
            float f1 = __uint_as_float(xh & 0xFFFF0000u);
            unsigned xl = cvt_pk_bf16(xpre.x - f0, xpre.y - f1);
            *(unsigned*)(db + lane * RS + 100) = xh;
            *(unsigned*)(db + lane * RS + 104) = xl;
            *(unsigned*)(db + lane * RS + 112) = xh;
            int t2 = (t + 2 < T_STEPS) ? t + 2 : T_STEPS - 1;
            xpre = *(const float2*)(xptr + (size_t)t2 * 2);
        }

        __syncthreads();
    };

    char* bufA = arena;
    char* bufB = arena + HBUF_SZ;
    for (int t = 0; t < T_STEPS; t += 2) {
        STEP(bufA, bufB, t);
        STEP(bufB, bufA, t + 1);
    }

    // ---- final FC from fp32 h regs ----
    float* hf = (float*)(arena + HF_OFF);   // [16][64]
#pragma unroll
    for (int tt = 0; tt < 2; ++tt) {
        if (!act[tt]) continue;
        const int u = (wvf * 2 + tt) * 4 + grp;
        if (u < HID) hf[col * 64 + u] = hreg[tt];
    }
    __syncthreads();
    if (tid < ROWS * 3) {
        int m = tid / 3, o = tid - m * 3;
        float s = b_fc[o];
        for (int k = 0; k < HID; ++k)
            s += hf[m * 64 + k] * W_fc[o * HID + k];
        out[(size_t)(b0 + m) * 3 + o] = s;
    }
}

extern "C" void kernel_launch(void* const* d_in, const int* in_sizes, int n_in,
                              void* d_out, int out_size, void* d_ws, size_t ws_size,
                              hipStream_t stream) {
    const float* x    = (const float*)d_in[0];
    const float* W_ih = (const float*)d_in[1];
    const float* W_hh = (const float*)d_in[2];
    const float* b_ih = (const float*)d_in[3];
    const float* b_hh = (const float*)d_in[4];
    const float* W_fc = (const float*)d_in[5];
    const float* b_fc = (const float*)d_in[6];
    float* out = (float*)d_out;

    dim3 grid(4096 / ROWS);   // 256 blocks -> 1 per CU
    dim3 block(NTHREADS);     // 8 waves (7 compute + 1 x-writer)
    lstm_mfma15_kernel<<<grid, block, 0, stream>>>(x, W_ih, W_hh, b_ih, b_hh,
                                                   W_fc, b_fc, out);
}

// Round 20
// 181.957 us; speedup vs baseline: 1.7338x; 1.1936x over previous
//
#include <hip/hip_runtime.h>

// LSTM B=4096, T=512, I=2, H=50, O=3 — MFMA, round 20.
// = r19 (best, 217us) + paired h-writes via INTERLEAVED unit mapping:
//   tile (w,tt) covers units 8w + 2*ulocal + tt  (even/odd interleave), so a
//   lane's two cells are ADJACENT units u0=8w+2*grp and u0+1. One
//   cvt_pk_bf16(h0,h1) + one ds_write_b32 replaces 2 cvt + 2 ds_write_b16
//   (DS write wave-ops halve; -2 V-ops/lane/t). Write mask u0<=48 keeps the
//   x/bias k-slots (>=50) untouched; pair {48,49} is the last real pair.
//   Wave 6's odd tile (incl. unit 49) becomes active -> all 7 compute waves
//   fully symmetric.
// Everything else identical to r19: single A-plane (W_hh bf16; x, bias,
// W_ih exact via K slots 50..57), 2 MFMA/tile chained through C, 8 waves
// (7 compute + wave-7 x-writer), RS=144, ONE barrier/t, exp2-direct
// pre-scaled-c' epilogue, static double-buffer unroll x2.

typedef short bf16x8 __attribute__((ext_vector_type(8)));
typedef float f32x4  __attribute__((ext_vector_type(4)));

#define T_STEPS 512
#define HID     50
#define ROWS    16
#define RS      144                        // bytes per m-row (9 granules)
#define HBUF_SZ (ROWS * RS)                // 2304 B
#define HF_OFF  (2 * HBUF_SZ)              // 4608 B
#define ARENA_SZ (HF_OFF + ROWS * 64 * 4)  // 8704 B
#define NTHREADS 512

#define L2E  1.442695040888963f
#define L2E2 2.885390081777927f

// init-time RTN bf16 hi/lo split (lo short = hi(f), hi short = residual)
__device__ __forceinline__ unsigned pack_hilo(float f) {
    unsigned u  = __float_as_uint(f);
    unsigned hi = (u + 0x7fffu + ((u >> 16) & 1u)) >> 16;
    float    fh = __uint_as_float(hi << 16);
    float    rl = f - fh;
    unsigned ul = __float_as_uint(rl);
    unsigned lo = (ul + 0x7fffu + ((ul >> 16) & 1u)) >> 16;
    return (hi & 0xFFFFu) | (lo << 16);
}
// 1-instr packed bf16 RNE: low short = bf16(a), high short = bf16(b)
__device__ __forceinline__ unsigned cvt_pk_bf16(float a, float b) {
    unsigned r;
    asm("v_cvt_pk_bf16_f32 %0, %1, %2" : "=v"(r) : "v"(a), "v"(b));
    return r;
}

__global__ __launch_bounds__(NTHREADS) void lstm_mfma16_kernel(
    const float* __restrict__ x,     // [B,T,2]
    const float* __restrict__ W_ih,  // [200,2]
    const float* __restrict__ W_hh,  // [200,50]
    const float* __restrict__ b_ih,  // [200]
    const float* __restrict__ b_hh,  // [200]
    const float* __restrict__ W_fc,  // [3,50]
    const float* __restrict__ b_fc,  // [3]
    float* __restrict__ out)         // [B,3]
{
    __shared__ __align__(16) char arena[ARENA_SZ];

    const int tid  = threadIdx.x;
    const int lane = tid & 63;
    const int wvf  = tid >> 6;         // wave 0..7
    const int col  = lane & 15;        // C col = batch row; A row index m
    const int grp  = lane >> 4;        // k-group; C row-group = unit-in-tile
    const int b0   = blockIdx.x * ROWS;

    // ---- zero arena ----
    for (int i = tid; i < ARENA_SZ / 4; i += NTHREADS) ((int*)arena)[i] = 0;

    // ---- A-frags (single plane, scaled) for tiles (wvf, tt) ----
    // INTERLEAVED unit map: row m=col -> unit u = 8*wvf + 2*(col>>2) + tt,
    // gate g = col&3.
    bf16x8 awf[2][2];   // [tt][kt]
    const bool compute = (wvf < 7);
#pragma unroll
    for (int tt = 0; tt < 2; ++tt) {
        const int u = 8 * wvf + 2 * (col >> 2) + tt;
        const int g = col & 3;
        const float s = (g == 2) ? L2E2 : -L2E;   // fold gate scale into W
#pragma unroll
        for (int kt = 0; kt < 2; ++kt) {
            bf16x8 F;
#pragma unroll
            for (int e = 0; e < 8; ++e) {
                int k = kt * 32 + grp * 8 + e;
                float v = 0.f;
                int  mode = 0;   // 0=zero, 1=hi(v*s), 2=lo(v*s)
                if (compute && u < HID) {
                    int j = g * HID + u;
                    if      (k < HID)  { v = W_hh[j * HID + k];     mode = 1; }
                    else if (k == 50 || k == 52) { v = W_ih[2*j+0]; mode = 1; }
                    else if (k == 51 || k == 53) { v = W_ih[2*j+1]; mode = 1; }
                    else if (k == 54)  { v = b_ih[j] + b_hh[j];     mode = 1; }
                    else if (k == 55)  { v = b_ih[j] + b_hh[j];     mode = 2; }
                    else if (k == 56)  { v = W_ih[2*j+0];           mode = 2; }
                    else if (k == 57)  { v = W_ih[2*j+1];           mode = 2; }
                }
                unsigned p = pack_hilo(v * s);
                F[e] = (mode == 2) ? (short)(p >> 16)
                                   : (mode == 1 ? (short)(p & 0xFFFFu) : (short)0);
            }
            awf[tt][kt] = F;
        }
    }

    __syncthreads();   // zeroing complete

    // bias multipliers: B = 1.0 at k=54 AND k=55 (bytes 108..111), both buffers
    if (tid < 2 * ROWS) {
        int buf = tid >> 4, m = tid & 15;
        *(unsigned*)(arena + buf * HBUF_SZ + m * RS + 108) = 0x3F803F80u;
    }
    // x writer: wave 7, lanes 0..15 (lane = batch row)
    const bool xwriter = (wvf == 7) && (lane < 16);
    const float* xptr = x + (size_t)(b0 + lane) * (T_STEPS * 2);
    if (xwriter) {   // x(t=0) into buffer 0
        float2 xv = *(const float2*)xptr;
        unsigned xh = cvt_pk_bf16(xv.x, xv.y);
        float f0 = __uint_as_float(xh << 16);
        float f1 = __uint_as_float(xh & 0xFFFF0000u);
        unsigned xl = cvt_pk_bf16(xv.x - f0, xv.y - f1);
        *(unsigned*)(arena + lane * RS + 100) = xh;   // k50/51 <- x hi
        *(unsigned*)(arena + lane * RS + 104) = xl;   // k52/53 <- x lo
        *(unsigned*)(arena + lane * RS + 112) = xh;   // k56/57 <- x hi (dup)
    }
    float2 xpre = xwriter ? *(const float2*)(xptr + 2) : make_float2(0.f, 0.f);

    float cp[2]   = {0.f, 0.f};    // c' = L2E2 * c (pre-scaled cell state)
    float hreg[2] = {0.f, 0.f};
    const int u0 = 8 * wvf + 2 * grp;          // my even unit (tt=0)
    const bool wrpair = compute && (u0 < HID - 1);   // pair {u0,u0+1} real

    __syncthreads();

    // ---- one timestep: read rb, write db (static pointers via unroll) ----
    auto STEP = [&](const char* rb, char* db, int t) {
        if (compute) {
            const char* hb = rb + col * RS + grp * 16;
            bf16x8 bh0 = *(const bf16x8*)(hb);
            bf16x8 bh1 = *(const bf16x8*)(hb + 64);

            f32x4 acc[2];
#pragma unroll
            for (int tt = 0; tt < 2; ++tt) {
                f32x4 a = {0.f, 0.f, 0.f, 0.f};   // 2 MFMA chained through C
                a = __builtin_amdgcn_mfma_f32_16x16x32_bf16(awf[tt][0], bh0, a, 0, 0, 0);
                a = __builtin_amdgcn_mfma_f32_16x16x32_bf16(awf[tt][1], bh1, a, 0, 0, 0);
                acc[tt] = a;
            }

#pragma unroll
            for (int tt = 0; tt < 2; ++tt) {
                float ei = __builtin_amdgcn_exp2f(acc[tt][0]);
                float ef = __builtin_amdgcn_exp2f(acc[tt][1]);
                float eg = __builtin_amdgcn_exp2f(acc[tt][2]);
                float eo = __builtin_amdgcn_exp2f(acc[tt][3]);
                float sf = __builtin_amdgcn_rcpf(1.0f + ef);
                float r  = __builtin_amdgcn_rcpf((1.0f + ei) * (eg + 1.0f));
                float t5 = fmaf(eg, L2E2, -L2E2);     // L2E2*(eg-1)
                float c  = fmaf(sf, cp[tt], t5 * r);  // c' = sf*c' + L2E2*ig_tg
                c = fminf(c, 92.0f);                  // upper clamp only
                cp[tt] = c;
                float ec = __builtin_amdgcn_exp2f(c); // = e^{2c_true}
                float h  = (ec - 1.0f) * __builtin_amdgcn_rcpf((1.0f + eo) * (ec + 1.0f));
                hreg[tt] = h;
            }

            // paired write: units u0 (low short) and u0+1 (high short)
            if (wrpair) {
                unsigned hp = cvt_pk_bf16(hreg[0], hreg[1]);
                *(unsigned*)(db + col * RS + u0 * 2) = hp;
            }
        }

        if (xwriter) {
            unsigned xh = cvt_pk_bf16(xpre.x, xpre.y);
            float f0 = __uint_as_float(xh << 16);
            float f1 = __uint_as_float(xh & 0xFFFF0000u);
            unsigned xl = cvt_pk_bf16(xpre.x - f0, xpre.y - f1);
            *(unsigned*)(db + lane * RS + 100) = xh;
            *(unsigned*)(db + lane * RS + 104) = xl;
            *(unsigned*)(db + lane * RS + 112) = xh;
            int t2 = (t + 2 < T_STEPS) ? t + 2 : T_STEPS - 1;
            xpre = *(const float2*)(xptr + (size_t)t2 * 2);
        }

        __syncthreads();
    };

    char* bufA = arena;
    char* bufB = arena + HBUF_SZ;
    for (int t = 0; t < T_STEPS; t += 2) {
        STEP(bufA, bufB, t);
        STEP(bufB, bufA, t + 1);
    }

    // ---- final FC from fp32 h regs ----
    float* hf = (float*)(arena + HF_OFF);   // [16][64]
    if (compute) {
#pragma unroll
        for (int tt = 0; tt < 2; ++tt) {
            const int u = u0 + tt;
            if (u < HID) hf[col * 64 + u] = hreg[tt];
        }
    }
    __syncthreads();
    if (tid < ROWS * 3) {
        int m = tid / 3, o = tid - m * 3;
        float s = b_fc[o];
        for (int k = 0; k < HID; ++k)
            s += hf[m * 64 + k] * W_fc[o * HID + k];
        out[(size_t)(b0 + m) * 3 + o] = s;
    }
}

extern "C" void kernel_launch(void* const* d_in, const int* in_sizes, int n_in,
                              void* d_out, int out_size, void* d_ws, size_t ws_size,
                              hipStream_t stream) {
    const float* x    = (const float*)d_in[0];
    const float* W_ih = (const float*)d_in[1];
    const float* W_hh = (const float*)d_in[2];
    const float* b_ih = (const float*)d_in[3];
    const float* b_hh = (const float*)d_in[4];
    const float* W_fc = (const float*)d_in[5];
    const float* b_fc = (const float*)d_in[6];
    float* out = (float*)d_out;

    dim3 grid(4096 / ROWS);   // 256 blocks -> 1 per CU
    dim3 block(NTHREADS);     // 8 waves (7 compute + 1 x-writer)
    lstm_mfma16_kernel<<<grid, block, 0, stream>>>(x, W_ih, W_hh, b_ih, b_hh,
                                                   W_fc, b_fc, out);
}